// Round 1
// baseline (3892.912 us; speedup 1.0000x reference)
//
#include <hip/hip_runtime.h>
#include <cstdint>
#include <cstddef>

// InterpAttentionKHeadsNet — fp32 correctness-first baseline.
// One 256-thread block per (b, nq): gather K=16 neighbor latents to LDS,
// 3x MLP layers + Q/V heads + softmax-over-K attention + final projection.
// Compute-bound (~180 GFLOP fp32); inputs (~21MB) fit L2/L3 so HBM ~idle.

#define NLAT 256
#define KNB 16
#define NHEAD 64

__device__ __forceinline__ void layer256(const float (*__restrict__ hin)[NLAT],
                                         float (*__restrict__ hout)[NLAT],
                                         const float* __restrict__ W,
                                         const float* __restrict__ bias,
                                         int c, bool do_relu) {
  const float* w = W + (size_t)c * NLAT;
  float acc[KNB];
#pragma unroll
  for (int k = 0; k < KNB; ++k) acc[k] = bias[c];
  for (int i = 0; i < NLAT; i += 4) {
    const float4 wv = *(const float4*)(w + i);
#pragma unroll
    for (int k = 0; k < KNB; ++k) {
      const float4 h = *(const float4*)(&hin[k][i]);  // LDS broadcast (uniform addr)
      acc[k] = fmaf(wv.x, h.x, acc[k]);
      acc[k] = fmaf(wv.y, h.y, acc[k]);
      acc[k] = fmaf(wv.z, h.z, acc[k]);
      acc[k] = fmaf(wv.w, h.w, acc[k]);
    }
  }
#pragma unroll
  for (int k = 0; k < KNB; ++k)
    hout[k][c] = do_relu ? fmaxf(acc[k], 0.f) : acc[k];
}

extern "C" __global__ __launch_bounds__(256, 3)
void interp_attn_kernel(const float* __restrict__ latents,  // [B,256,N]
                        const float* __restrict__ pts,      // [B,3,N]
                        const float* __restrict__ ptsq,     // [B,3,NQ]
                        const void*  __restrict__ proj_ids, // [B,NQ,16] i32 or i64
                        const float* __restrict__ W1, const float* __restrict__ b1,
                        const float* __restrict__ W2, const float* __restrict__ b2,
                        const float* __restrict__ W3, const float* __restrict__ b3,
                        const float* __restrict__ Wq, const float* __restrict__ bq,
                        const float* __restrict__ Wv, const float* __restrict__ bv,
                        const float* __restrict__ W8, const float* __restrict__ b8,
                        float* __restrict__ out,            // [B,1,NQ]
                        int B, int N, int NQ) {
  __shared__ float bufA[KNB][NLAT];          // 16 KB
  __shared__ float bufB[KNB][NLAT];          // 16 KB
  __shared__ float qpart[4][NHEAD][KNB];     // 16 KB (reused for softmax scratch)
  __shared__ float rel[KNB][3];
  __shared__ int   sidx[KNB];
  __shared__ float att[KNB];
  __shared__ float wred[4];
  __shared__ int   idx_is64;

  const int tid = threadIdx.x;
  const int bid = blockIdx.x;
  const int b  = bid / NQ;
  const int nq = bid - b * NQ;

  // Runtime dtype probe for proj_ids: if int64, every high dword is 0
  // (values < N=10000). 64 samples -> false-positive prob ~0 for int32.
  if (tid == 0) {
    const int* p = (const int*)proj_ids;
    int z = 1;
    for (int i = 0; i < 64; ++i) z &= (p[2 * i + 1] == 0);
    idx_is64 = z;
  }
  __syncthreads();

  if (tid < KNB) {
    long long base = ((long long)b * NQ + nq) * KNB + tid;
    int id;
    if (idx_is64) id = (int)((const long long*)proj_ids)[base];
    else          id = ((const int*)proj_ids)[base];
    sidx[tid] = id;
  }
  __syncthreads();

  if (tid < KNB * 3) {
    int k = tid / 3, j = tid - 3 * k;
    rel[k][j] = ptsq[((size_t)b * 3 + j) * NQ + nq]
              - pts[((size_t)b * 3 + j) * N + sidx[k]];
  }
  {
    const float* latb = latents + (size_t)b * NLAT * N + (size_t)tid * N;
#pragma unroll
    for (int k = 0; k < KNB; ++k) bufA[k][tid] = latb[sidx[k]];  // gather (L2/L3 hit)
  }
  __syncthreads();

  // ---- Layer 1: (256 latent + 3 rel) -> 256, ReLU ----
  {
    const int c = tid;
    const float* w = W1 + (size_t)c * 259;  // rows not 16B-aligned: scalar loads
    float acc[KNB];
#pragma unroll
    for (int k = 0; k < KNB; ++k) acc[k] = b1[c];
    for (int i = 0; i < NLAT; i += 4) {
      float w0 = w[i], w1_ = w[i + 1], w2_ = w[i + 2], w3_ = w[i + 3];
#pragma unroll
      for (int k = 0; k < KNB; ++k) {
        const float4 h = *(const float4*)(&bufA[k][i]);
        acc[k] = fmaf(w0, h.x, acc[k]);
        acc[k] = fmaf(w1_, h.y, acc[k]);
        acc[k] = fmaf(w2_, h.z, acc[k]);
        acc[k] = fmaf(w3_, h.w, acc[k]);
      }
    }
    float wr0 = w[256], wr1 = w[257], wr2 = w[258];
#pragma unroll
    for (int k = 0; k < KNB; ++k) {
      float v = acc[k] + wr0 * rel[k][0] + wr1 * rel[k][1] + wr2 * rel[k][2];
      bufB[k][c] = fmaxf(v, 0.f);
    }
  }
  __syncthreads();

  // ---- Layer 2, Layer 3 ----
  layer256(bufB, bufA, W2, b2, tid, true);
  __syncthreads();
  layer256(bufA, bufB, W3, b3, tid, true);
  __syncthreads();

  // ---- Q heads: thread = (head h, i-chunk j); 4-way split over input dim ----
  {
    const int h = tid & 63, j = tid >> 6;
    const float* w = Wq + (size_t)h * NLAT + j * 64;
    float acc[KNB];
#pragma unroll
    for (int k = 0; k < KNB; ++k) acc[k] = 0.f;
    for (int i = 0; i < 64; i += 4) {
      const float4 wv = *(const float4*)(w + i);
#pragma unroll
      for (int k = 0; k < KNB; ++k) {
        const float4 hh = *(const float4*)(&bufB[k][j * 64 + i]);
        acc[k] = fmaf(wv.x, hh.x, acc[k]);
        acc[k] = fmaf(wv.y, hh.y, acc[k]);
        acc[k] = fmaf(wv.z, hh.z, acc[k]);
        acc[k] = fmaf(wv.w, hh.w, acc[k]);
      }
    }
#pragma unroll
    for (int k = 0; k < KNB; ++k) qpart[j][h][k] = acc[k];
  }

  // ---- V: bufB -> bufA (no relu) ----
  layer256(bufB, bufA, Wv, bv, tid, false);
  __syncthreads();

  // ---- softmax over K per head (lanes 0..63), then mean over heads ----
  float e[KNB];
  float inv_s = 0.f;
  if (tid < NHEAD) {
    float q[KNB];
#pragma unroll
    for (int k = 0; k < KNB; ++k)
      q[k] = qpart[0][tid][k] + qpart[1][tid][k] + qpart[2][tid][k] + qpart[3][tid][k]
           + bq[tid];
    float m = q[0];
#pragma unroll
    for (int k = 1; k < KNB; ++k) m = fmaxf(m, q[k]);
    float s = 0.f;
#pragma unroll
    for (int k = 0; k < KNB; ++k) { e[k] = expf(q[k] - m); s += e[k]; }
    inv_s = 1.f / s;
  }
  __syncthreads();  // all qpart reads done before overwrite
  if (tid < NHEAD) {
#pragma unroll
    for (int k = 0; k < KNB; ++k) qpart[0][tid][k] = e[k] * inv_s;
  }
  __syncthreads();
  if (tid < KNB) {
    float s = 0.f;
#pragma unroll
    for (int h = 0; h < NHEAD; ++h) s += qpart[0][h][tid];
    att[tid] = s * (1.f / 64.f);
  }
  __syncthreads();

  // ---- weighted sum over K, then W8 dot (reduce over 256 channels) ----
  float po = 0.f;
#pragma unroll
  for (int k = 0; k < KNB; ++k) po = fmaf(att[k], bufA[k][tid], po);
  float val = W8[tid] * po;
#pragma unroll
  for (int off = 32; off > 0; off >>= 1) val += __shfl_down(val, off);
  if ((tid & 63) == 0) wred[tid >> 6] = val;
  __syncthreads();
  if (tid == 0)
    out[(size_t)b * NQ + nq] = wred[0] + wred[1] + wred[2] + wred[3] + b8[0];
}

extern "C" void kernel_launch(void* const* d_in, const int* in_sizes, int n_in,
                              void* d_out, int out_size, void* d_ws, size_t ws_size,
                              hipStream_t stream) {
  const float* latents = (const float*)d_in[0];
  const float* pts     = (const float*)d_in[1];
  const float* ptsq    = (const float*)d_in[2];
  const void*  proj    = d_in[3];
  const float* W1 = (const float*)d_in[4];
  const float* b1 = (const float*)d_in[5];
  const float* W2 = (const float*)d_in[6];
  const float* b2 = (const float*)d_in[7];
  const float* W3 = (const float*)d_in[8];
  const float* b3 = (const float*)d_in[9];
  const float* Wq = (const float*)d_in[10];
  const float* bq = (const float*)d_in[11];
  const float* Wv = (const float*)d_in[12];
  const float* bv = (const float*)d_in[13];
  const float* W8 = (const float*)d_in[14];
  const float* b8 = (const float*)d_in[15];
  float* out = (float*)d_out;

  const int B  = 2;                       // fixed by setup_inputs
  const int N  = in_sizes[1] / (3 * B);   // pts: [B,3,N]
  const int NQ = in_sizes[2] / (3 * B);   // pts_query: [B,3,NQ]

  dim3 grid(B * NQ), block(256);
  hipLaunchKernelGGL(interp_attn_kernel, grid, block, 0, stream,
                     latents, pts, ptsq, proj,
                     W1, b1, W2, b2, W3, b3, Wq, bq, Wv, bv, W8, b8,
                     out, B, N, NQ);
}

// Round 2
// 338.919 us; speedup vs baseline: 11.4863x; 11.4863x over previous
//
#include <hip/hip_runtime.h>
#include <cstdint>
#include <cstddef>

// InterpAttentionKHeadsNet — fp16 MFMA version.
// Block = 4 queries x 16 neighbors = 64 rows. Per layer each of 4 waves
// computes C'[64ch][64m] = W x H^T via mfma_f32_16x16x32_f16.
// V-layer folded into wv8 = W8*Wv (att sums to 1). Layer-1 rel channels
// handled as a 9th zero-padded k-step. LDS tiles XOR-swizzled per 16B chunk.

#define NLAT 256
#define KNB 16
#define QB 4
#define MROWS 64      // QB*KNB
#define ROWCH 36      // 32 latent chunks + 1 rel + 3 zero
#define ROWB 576      // ROWCH*16 bytes per row

typedef float    f32x4 __attribute__((ext_vector_type(4)));
typedef _Float16 f16x8 __attribute__((ext_vector_type(8)));
typedef _Float16 f16x4 __attribute__((ext_vector_type(4)));

__device__ __forceinline__ int swzc(int c, int row) {
  return (c < 32) ? (c ^ (row & 7)) : (32 + ((c - 32) ^ (row & 3)));
}
__device__ __forceinline__ int lbyte(int row, int c) {
  return row * ROWB + swzc(c, row) * 16;
}

struct AtT {
  float Qs[64][66];   // [head][m], padded stride
  float S[MROWS];
  float Sp[4][MROWS];
};
struct Smem {
  union {
    unsigned char A[MROWS * ROWB];  // 36864 B; aliased by AtT after layer 3
    AtT at;
  };
  unsigned char B[MROWS * ROWB];    // 36864 B
  int sidx[MROWS];
  int is64;
};

// C'[ch 256][m 64] = Wb(fp16 [256][256]) x Hin^T ; +bias, opt relu, fp16 -> hout.
__device__ __forceinline__ void layer_mfma(
    const unsigned char* hin, unsigned char* hout,
    const unsigned short* __restrict__ Wb_u, const float* __restrict__ bias,
    const float* __restrict__ W1tail,  // non-null only for layer 1 (fp32 [256][259])
    int lane, int wave, bool relu)
{
  const _Float16* Wb = (const _Float16*)Wb_u;
  const int lm = lane & 15, lk = lane >> 4;
  f32x4 acc[4][4];
#pragma unroll
  for (int i = 0; i < 4; ++i)
#pragma unroll
    for (int j = 0; j < 4; ++j) acc[i][j] = (f32x4){0.f, 0.f, 0.f, 0.f};

#pragma unroll
  for (int ks = 0; ks < 8; ++ks) {
    f16x8 a[4], bf[4];
#pragma unroll
    for (int ct = 0; ct < 4; ++ct) {
      int ch = wave * 64 + ct * 16 + lm;
      a[ct] = *(const f16x8*)(Wb + (size_t)ch * NLAT + ks * 32 + lk * 8);
    }
#pragma unroll
    for (int mt = 0; mt < 4; ++mt)
      bf[mt] = *(const f16x8*)(hin + lbyte(mt * 16 + lm, ks * 4 + lk));
#pragma unroll
    for (int ct = 0; ct < 4; ++ct)
#pragma unroll
      for (int mt = 0; mt < 4; ++mt)
        acc[ct][mt] = __builtin_amdgcn_mfma_f32_16x16x32_f16(a[ct], bf[mt], acc[ct][mt], 0, 0, 0);
  }
  if (W1tail) {  // 9th k-step: k = 256..287 (rel channels, zero padded)
    f16x8 a[4], bf[4];
#pragma unroll
    for (int ct = 0; ct < 4; ++ct) {
      f16x8 v = {0, 0, 0, 0, 0, 0, 0, 0};
      if (lk == 0) {
        int ch = wave * 64 + ct * 16 + lm;
        const float* wt = W1tail + (size_t)ch * 259 + 256;
        v[0] = (_Float16)wt[0]; v[1] = (_Float16)wt[1]; v[2] = (_Float16)wt[2];
      }
      a[ct] = v;
    }
#pragma unroll
    for (int mt = 0; mt < 4; ++mt)
      bf[mt] = *(const f16x8*)(hin + lbyte(mt * 16 + lm, 32 + lk));
#pragma unroll
    for (int ct = 0; ct < 4; ++ct)
#pragma unroll
      for (int mt = 0; mt < 4; ++mt)
        acc[ct][mt] = __builtin_amdgcn_mfma_f32_16x16x32_f16(a[ct], bf[mt], acc[ct][mt], 0, 0, 0);
  }
  // epilogue: bias (+relu), convert to fp16, write H'[m][ch] (4 ch contiguous)
#pragma unroll
  for (int ct = 0; ct < 4; ++ct) {
    const int ch0 = wave * 64 + ct * 16 + lk * 4;
    float bsv[4];
#pragma unroll
    for (int r = 0; r < 4; ++r) bsv[r] = bias[ch0 + r];
#pragma unroll
    for (int mt = 0; mt < 4; ++mt) {
      const int row = mt * 16 + lm;
      f16x4 v;
#pragma unroll
      for (int r = 0; r < 4; ++r) {
        float x = acc[ct][mt][r] + bsv[r];
        if (relu) x = fmaxf(x, 0.f);
        v[r] = (_Float16)x;
      }
      const int byte = row * ROWB + swzc(ch0 >> 3, row) * 16 + (ch0 & 7) * 2;
      *(f16x4*)(hout + byte) = v;
    }
  }
}

extern "C" __global__ __launch_bounds__(256, 2)
void interp_mfma(const float* __restrict__ latents,
                 const float* __restrict__ pts,
                 const float* __restrict__ ptsq,
                 const void*  __restrict__ proj,
                 const unsigned short* __restrict__ Lt_u,   // fp16 [B][N][256]
                 const float* __restrict__ W1f,             // fp32 [256][259]
                 const unsigned short* __restrict__ W1h,
                 const unsigned short* __restrict__ W2h,
                 const unsigned short* __restrict__ W3h,
                 const unsigned short* __restrict__ Wqh,    // fp16 [64][256]
                 const float* __restrict__ b1, const float* __restrict__ b2,
                 const float* __restrict__ b3, const float* __restrict__ bq,
                 const float* __restrict__ wv8, const float* __restrict__ c0p,
                 float* __restrict__ out,
                 int N, int NQ, int use_lt)
{
  __shared__ Smem sm;
  const int tid = threadIdx.x;
  const int bid = blockIdx.x;
  const int lane = tid & 63, wave = tid >> 6;

  if (tid == 0) {
    const int* p = (const int*)proj;
    int z = 1;
    for (int i = 0; i < 64; ++i) z &= (p[2 * i + 1] == 0);
    sm.is64 = z;
  }
  __syncthreads();
  if (tid < MROWS) {
    long long g = (long long)bid * QB + (tid >> 4);
    long long base = g * KNB + (tid & 15);
    sm.sidx[tid] = sm.is64 ? (int)((const long long*)proj)[base]
                           : ((const int*)proj)[base];
  }
  __syncthreads();

  // ---- gather: fill row (64 latent chunks->fp16) + rel chunk + zeros ----
  {
    const int row = tid >> 2, part = tid & 3;
    const int id = sm.sidx[row];
    const long long g = (long long)bid * QB + (row >> 4);
    const int b = (int)(g / NQ);
    if (use_lt) {
      const _Float16* src = (const _Float16*)Lt_u + ((size_t)b * N + id) * NLAT + part * 64;
#pragma unroll
      for (int cc = 0; cc < 8; ++cc)
        *(f16x8*)(sm.A + lbyte(row, part * 8 + cc)) = *(const f16x8*)(src + cc * 8);
    } else {
      for (int cc = 0; cc < 8; ++cc) {
        f16x8 v;
#pragma unroll
        for (int j = 0; j < 8; ++j) {
          int ch = part * 64 + cc * 8 + j;
          v[j] = (_Float16)latents[((size_t)b * NLAT + ch) * N + id];
        }
        *(f16x8*)(sm.A + lbyte(row, part * 8 + cc)) = v;
      }
    }
    if (part == 0) {
      const int nq = (int)(g - (long long)b * NQ);
      f16x8 v = {0, 0, 0, 0, 0, 0, 0, 0};
#pragma unroll
      for (int j = 0; j < 3; ++j)
        v[j] = (_Float16)(ptsq[((size_t)b * 3 + j) * NQ + nq]
                        - pts[((size_t)b * 3 + j) * N + id]);
      *(f16x8*)(sm.A + lbyte(row, 32)) = v;
    } else {
      f16x8 z = {0, 0, 0, 0, 0, 0, 0, 0};
      *(f16x8*)(sm.A + lbyte(row, 32 + part)) = z;
    }
  }
  __syncthreads();

  layer_mfma(sm.A, sm.B, W1h, b1, W1f, lane, wave, true);   // L1 (K=259)
  __syncthreads();
  layer_mfma(sm.B, sm.A, W2h, b2, nullptr, lane, wave, true);
  __syncthreads();
  layer_mfma(sm.A, sm.B, W3h, b3, nullptr, lane, wave, true); // H3 -> sm.B
  __syncthreads();

  // ---- Q heads: C'[64 head][64 m]; wave owns 16 heads. Writes Qs (aliases A) ----
  {
    const int lm = lane & 15, lk = lane >> 4;
    const _Float16* Wq16 = (const _Float16*)Wqh;
    f32x4 qacc[4];
#pragma unroll
    for (int mt = 0; mt < 4; ++mt) qacc[mt] = (f32x4){0.f, 0.f, 0.f, 0.f};
#pragma unroll
    for (int ks = 0; ks < 8; ++ks) {
      const int h = wave * 16 + lm;
      f16x8 a = *(const f16x8*)(Wq16 + (size_t)h * NLAT + ks * 32 + lk * 8);
#pragma unroll
      for (int mt = 0; mt < 4; ++mt) {
        f16x8 bf = *(const f16x8*)(sm.B + lbyte(mt * 16 + lm, ks * 4 + lk));
        qacc[mt] = __builtin_amdgcn_mfma_f32_16x16x32_f16(a, bf, qacc[mt], 0, 0, 0);
      }
    }
    float bqv[4];
#pragma unroll
    for (int r = 0; r < 4; ++r) bqv[r] = bq[wave * 16 + lk * 4 + r];
#pragma unroll
    for (int mt = 0; mt < 4; ++mt)
#pragma unroll
      for (int r = 0; r < 4; ++r)
        sm.at.Qs[wave * 16 + lk * 4 + r][mt * 16 + lm] = qacc[mt][r] + bqv[r];
  }
  // ---- S partials: S[m] = H3[m] . wv8 ----
  {
    const int m = lane, qr = wave;
    float sacc = 0.f;
#pragma unroll
    for (int cc = 0; cc < 8; ++cc) {
      const int c = qr * 8 + cc;
      f16x8 v = *(const f16x8*)(sm.B + lbyte(m, c));
#pragma unroll
      for (int e = 0; e < 8; ++e) sacc += (float)v[e] * wv8[c * 8 + e];
    }
    sm.at.Sp[qr][m] = sacc;
  }
  __syncthreads();
  if (tid < MROWS)
    sm.at.S[tid] = sm.at.Sp[0][tid] + sm.at.Sp[1][tid] + sm.at.Sp[2][tid] + sm.at.Sp[3][tid];
  __syncthreads();

  // ---- softmax over K per head, mean over heads, project ----
  {
    float qv[KNB], mx = -1e30f;
#pragma unroll
    for (int nb = 0; nb < KNB; ++nb) {
      qv[nb] = sm.at.Qs[lane][wave * 16 + nb];
      mx = fmaxf(mx, qv[nb]);
    }
    float sum = 0.f, val = 0.f;
#pragma unroll
    for (int nb = 0; nb < KNB; ++nb) {
      float e = expf(qv[nb] - mx);
      sum += e;
      val += e * sm.at.S[wave * 16 + nb];
    }
    val /= sum;
#pragma unroll
    for (int off = 32; off; off >>= 1) val += __shfl_down(val, off);
    if (lane == 0) out[(long long)bid * QB + wave] = val * (1.f / 64.f) + c0p[0];
  }
}

// ---- prep: fp32 weights -> fp16; wv8 = W8*Wv fold; c0 = b8 + W8.bv ----
extern "C" __global__ void prep_w(const float* __restrict__ W1, const float* __restrict__ W2,
                                  const float* __restrict__ W3, const float* __restrict__ Wq,
                                  const float* __restrict__ Wv, const float* __restrict__ W8,
                                  const float* __restrict__ bv, const float* __restrict__ b8,
                                  unsigned short* W1h, unsigned short* W2h,
                                  unsigned short* W3h, unsigned short* Wqh,
                                  float* wv8, float* c0) {
  const int t = blockIdx.x * 256 + threadIdx.x;
  union { _Float16 h; unsigned short u; } cv;
  if (t < 65536) {
    const int ch = t >> 8, k = t & 255;
    cv.h = (_Float16)W1[(size_t)ch * 259 + k]; W1h[t] = cv.u;
    cv.h = (_Float16)W2[t]; W2h[t] = cv.u;
    cv.h = (_Float16)W3[t]; W3h[t] = cv.u;
  }
  if (t < 16384) { cv.h = (_Float16)Wq[t]; Wqh[t] = cv.u; }
  if (t < 256) {
    float s = 0.f;
    for (int o = 0; o < 256; ++o) s += Wv[(size_t)o * 256 + t] * W8[o];
    wv8[t] = s;
  }
  if (t == 0) {
    float s = 0.f;
    for (int o = 0; o < 256; ++o) s += bv[o] * W8[o];
    c0[0] = s + b8[0];
  }
}

// ---- transpose latents [B][256][N] -> fp16 [B][N][256] ----
extern "C" __global__ void transp(const float* __restrict__ latents,
                                  unsigned short* __restrict__ Lt, int N) {
  __shared__ unsigned short tile[256][68];
  const int b = blockIdx.y, n0 = blockIdx.x * 64, tid = threadIdx.x;
  const int nl = tid & 63;
  union { _Float16 h; unsigned short u; } cv;
  for (int c = tid >> 6; c < 256; c += 4) {
    const int n = n0 + nl;
    float v = (n < N) ? latents[((size_t)b * NLAT + c) * N + n] : 0.f;
    cv.h = (_Float16)v;
    tile[c][nl] = cv.u;
  }
  __syncthreads();
  const int nr = tid >> 2, cg = (tid & 3) * 64;
  const int n = n0 + nr;
  if (n < N) {
    for (int cc = 0; cc < 64; cc += 8) {
      f16x8 v;
#pragma unroll
      for (int j = 0; j < 8; ++j) {
        union { unsigned short u; _Float16 h; } bk;
        bk.u = tile[cg + cc + j][nr];
        v[j] = bk.h;
      }
      *(f16x8*)((_Float16*)Lt + ((size_t)b * N + n) * NLAT + cg + cc) = v;
    }
  }
}

extern "C" void kernel_launch(void* const* d_in, const int* in_sizes, int n_in,
                              void* d_out, int out_size, void* d_ws, size_t ws_size,
                              hipStream_t stream) {
  (void)n_in; (void)out_size;
  const float* latents = (const float*)d_in[0];
  const float* pts     = (const float*)d_in[1];
  const float* ptsq    = (const float*)d_in[2];
  const void*  proj    = d_in[3];
  const float* W1 = (const float*)d_in[4];  const float* b1 = (const float*)d_in[5];
  const float* W2 = (const float*)d_in[6];  const float* b2 = (const float*)d_in[7];
  const float* W3 = (const float*)d_in[8];  const float* b3 = (const float*)d_in[9];
  const float* Wq = (const float*)d_in[10]; const float* bq = (const float*)d_in[11];
  const float* Wv = (const float*)d_in[12]; const float* bv = (const float*)d_in[13];
  const float* W8 = (const float*)d_in[14]; const float* b8 = (const float*)d_in[15];
  float* out = (float*)d_out;

  const int B  = 2;
  const int N  = in_sizes[1] / (3 * B);
  const int NQ = in_sizes[2] / (3 * B);

  size_t off = 0;
  auto alloc = [&](size_t bytes) -> char* {
    char* p = (char*)d_ws + off;
    off += (bytes + 255) & ~(size_t)255;
    return p;
  };
  unsigned short* W1h = (unsigned short*)alloc(65536 * 2);
  unsigned short* W2h = (unsigned short*)alloc(65536 * 2);
  unsigned short* W3h = (unsigned short*)alloc(65536 * 2);
  unsigned short* Wqh = (unsigned short*)alloc(16384 * 2);
  float* wv8 = (float*)alloc(256 * 4);
  float* c0  = (float*)alloc(4);
  const size_t lt_bytes = (size_t)B * N * NLAT * 2;
  unsigned short* Lt = (unsigned short*)((char*)d_ws + off);
  const int use_lt = (off + lt_bytes <= ws_size) ? 1 : 0;

  hipLaunchKernelGGL(prep_w, dim3(256), dim3(256), 0, stream,
                     W1, W2, W3, Wq, Wv, W8, bv, b8, W1h, W2h, W3h, Wqh, wv8, c0);
  if (use_lt)
    hipLaunchKernelGGL(transp, dim3((N + 63) / 64, B), dim3(256), 0, stream,
                       latents, Lt, N);
  const int nblocks = (B * NQ + QB - 1) / QB;
  hipLaunchKernelGGL(interp_mfma, dim3(nblocks), dim3(256), 0, stream,
                     latents, pts, ptsq, proj, Lt, W1, W1h, W2h, W3h, Wqh,
                     b1, b2, b3, bq, wv8, c0, out, N, NQ, use_lt);
}